// Round 8
// baseline (235.977 us; speedup 1.0000x reference)
//
#include <hip/hip_runtime.h>
#include <math.h>

#define C_CAND 10

typedef float vf3 __attribute__((ext_vector_type(3), aligned(4)));
typedef int   vi3 __attribute__((ext_vector_type(3), aligned(4)));
typedef float v4f __attribute__((ext_vector_type(4)));  // 16B, aligned

// Bit-identical point-triangle "merged distance". Op order mirrors numpy
// exactly; contract(off) forbids FMA fusion (IEEE div/sqrt match numpy).
__device__ __forceinline__ float tri_merged(
    float qx, float qy, float qz,
    float v0x, float v0y, float v0z,
    float v1x, float v1y, float v1z,
    float v2x, float v2y, float v2z)
{
#pragma clang fp contract(off)
    const float e10x = v1x - v0x, e10y = v1y - v0y, e10z = v1z - v0z;
    const float e21x = v2x - v1x, e21y = v2y - v1y, e21z = v2z - v1z;
    const float e02x = v0x - v2x, e02y = v0y - v2y, e02z = v0z - v2z;

    const float crx = e10y*e02z - e10z*e02y;
    const float cry = e10z*e02x - e10x*e02z;
    const float crz = e10x*e02y - e10y*e02x;
    const float fNx = -crx, fNy = -cry, fNz = -crz;

    const float a0x = qx - v0x, a0y = qy - v0y, a0z = qz - v0z;
    const float a1x = qx - v1x, a1y = qy - v1y, a1z = qz - v1z;
    const float a2x = qx - v2x, a2y = qy - v2y, a2z = qz - v2z;

    const float num_ab = (a0x*e10x + a0y*e10y) + a0z*e10z;
    const float den_ab = fmaxf((e10x*e10x + e10y*e10y) + e10z*e10z, 1e-9f);
    const float uab = num_ab / den_ab;

    const float num_bc = (a1x*e21x + a1y*e21y) + a1z*e21z;
    const float den_bc = fmaxf((e21x*e21x + e21y*e21y) + e21z*e21z, 1e-9f);
    const float ubc = num_bc / den_bc;

    const float num_ca = (a2x*e02x + a2y*e02y) + a2z*e02z;
    const float den_ca = fmaxf((e02x*e02x + e02y*e02y) + e02z*e02z, 1e-9f);
    const float uca = num_ca / den_ca;

    const bool t1 = (uca > 1.0f) && (uab < 0.0f);
    const bool t2 = (uab > 1.0f) && (ubc < 0.0f);
    const bool t3 = (ubc > 1.0f) && (uca < 0.0f);

    const float c0x = fNy*e10z - fNz*e10y;
    const float c0y = fNz*e10x - fNx*e10z;
    const float c0z = fNx*e10y - fNy*e10x;
    const bool na0 = ((c0x*a0x + c0y*a0y) + c0z*a0z) <= 0.0f;

    const float c1x = fNy*e21z - fNz*e21y;
    const float c1y = fNz*e21x - fNx*e21z;
    const float c1z = fNx*e21y - fNy*e21x;
    const bool na1 = ((c1x*a1x + c1y*a1y) + c1z*a1z) <= 0.0f;

    const float c2x = fNy*e02z - fNz*e02y;
    const float c2y = fNz*e02x - fNx*e02z;
    const float c2z = fNx*e02y - fNy*e02x;
    const bool na2 = ((c2x*a2x + c2y*a2y) + c2z*a2z) <= 0.0f;

    const bool t4 = (uab >= 0.0f) && (uab <= 1.0f) && na0;
    const bool t5 = (ubc >= 0.0f) && (ubc <= 1.0f) && na1 && !t4;
    const bool t6 = (uca >= 0.0f) && (uca <= 1.0f) && na2 && !t4 && !t5;
    const bool t0 = !(t1 || t2 || t3 || t4 || t5 || t6);

    const float nrm = sqrtf((fNx*fNx + fNy*fNy) + fNz*fNz);
    const float dnm = fmaxf(nrm, 1e-9f);
    const float unx = fNx / dnm;
    const float uny = fNy / dnm;
    const float unz = fNz / dnm;

    const float d0 = (a0x*unx + a0y*uny) + a0z*unz;
    const float d1 = sqrtf((a0x*a0x + a0y*a0y) + a0z*a0z);
    const float d2 = sqrtf((a1x*a1x + a1y*a1y) + a1z*a1z);
    const float d3 = sqrtf((a2x*a2x + a2y*a2y) + a2z*a2z);

    const float p4x = v0x + e10x*uab, p4y = v0y + e10y*uab, p4z = v0z + e10z*uab;
    const float p5x = v1x + e21x*ubc, p5y = v1y + e21y*ubc, p5z = v1z + e21z*ubc;
    const float p6x = v2x + e02x*uca, p6y = v2y + e02y*uca, p6z = v2z + e02z*uca;

    const float g4x = qx - p4x, g4y = qy - p4y, g4z = qz - p4z;
    const float g5x = qx - p5x, g5y = qy - p5y, g5z = qz - p5z;
    const float g6x = qx - p6x, g6y = qy - p6y, g6z = qz - p6z;

    const float d4 = sqrtf((g4x*g4x + g4y*g4y) + g4z*g4z);
    const float d5 = sqrtf((g5x*g5x + g5y*g5y) + g5z*g5z);
    const float d6 = sqrtf((g6x*g6x + g6y*g6y) + g6z*g6z);

    float merged = d0 * (t0 ? 1.0f : 0.0f);
    merged = merged + d1 * (t1 ? 1.0f : 0.0f);
    merged = merged + d2 * (t2 ? 1.0f : 0.0f);
    merged = merged + d3 * (t3 ? 1.0f : 0.0f);
    merged = merged + d4 * (t4 ? 1.0f : 0.0f);
    merged = merged + d5 * (t5 ? 1.0f : 0.0f);
    merged = merged + d6 * (t6 ? 1.0f : 0.0f);
    return merged;
}

// -------- Pass 1: pack 9 vertex floats per face into a 64B-stride record.
__global__ __launch_bounds__(256) void pack_faces_kernel(
    const float* __restrict__ temp_verts,
    const int*   __restrict__ faces,
    float*       __restrict__ packed,
    int F)
{
    int t = blockIdx.x * blockDim.x + threadIdx.x;
    if (t >= F) return;

    const vi3 fi = *(const vi3*)(faces + 3*t);
    const vf3 v0 = *(const vf3*)(temp_verts + 3*fi.x);
    const vf3 v1 = *(const vf3*)(temp_verts + 3*fi.y);
    const vf3 v2 = *(const vf3*)(temp_verts + 3*fi.z);

    v4f* dst = (v4f*)(packed + (size_t)16 * t);
    v4f a; a.x = v0.x; a.y = v0.y; a.z = v0.z; a.w = v1.x;
    v4f b; b.x = v1.y; b.y = v1.z; b.z = v2.x; b.w = v2.y;
    v4f c; c.x = v2.z; c.y = 0.0f; c.z = 0.0f; c.w = 0.0f;
    dst[0] = a; dst[1] = b; dst[2] = c;
}

// -------- keys init (graph-safe fill; harness poisons ws every call).
__global__ __launch_bounds__(256) void fill_keys_kernel(
    unsigned long long* __restrict__ keys, int n)
{
    int i = blockIdx.x * blockDim.x + threadIdx.x;
    if (i < n) keys[i] = ~0ull;
}

// -------- Pass 2 (sliced): slice = blockIdx%4 so, under round-robin
// blockIdx%8 -> XCD dispatch, each XCD only gathers from a 3.2MB table
// slice that FITS its 4MiB L2 (R7: unsliced 12.8MB table -> reuse distance
// = table size -> 0% hit -> 316MB miss traffic at 3.2TB/s = the whole 98us).
// Wave-level ballot-compaction keeps total tri_merged issue count unchanged
// (naive slicing would 4x the exec-masked VALU). Per-candidate argmin merge
// via u64 atomicMin on key (am_bits<<32 | j<<18 | f): monotone in |merged|,
// first-j tie-break == np.argmin.
__global__ __launch_bounds__(256) void woot_sliced_kernel(
    const float* __restrict__ query_xyz,
    const float* __restrict__ packed,
    const int*   __restrict__ cand_ids,
    unsigned long long* __restrict__ keys,
    int n, int Fs, int F)
{
    const int slice  = blockIdx.x & 3;
    const int qblock = blockIdx.x >> 2;
    const int tid    = threadIdx.x;
    const int lane   = tid & 63;
    const int wid    = tid >> 6;
    const int qi     = qblock * 256 + tid;

    __shared__ float qs0[256], qs1[256], qs2[256];
    __shared__ unsigned int queue[4][640];

    const int lo = slice * Fs;
    const int hi = (lo + Fs < F) ? (lo + Fs) : F;

    const bool valid = qi < n;
    if (valid) {
        const vf3 q = __builtin_nontemporal_load((const vf3*)(query_xyz + 3*qi));
        qs0[tid] = q.x; qs1[tid] = q.y; qs2[tid] = q.z;
    }

    // Filter: ballot-compact this wave's in-slice candidates into its queue.
    unsigned int cnt = 0;   // wave-uniform
    for (int j = 0; j < C_CAND; ++j) {
        int f = -1;
        if (valid) f = __builtin_nontemporal_load(&cand_ids[qi * C_CAND + j]);
        const bool in = valid && (f >= lo) && (f < hi);
        const unsigned long long m = __ballot(in);
        if (in) {
            const unsigned long long below = (1ull << lane) - 1ull;
            const unsigned int pos = cnt + (unsigned)__popcll(m & below);
            queue[wid][pos] = (unsigned)f | ((unsigned)j << 18)
                                          | ((unsigned)lane << 22);
        }
        cnt += (unsigned)__popcll(m);
    }

    __syncthreads();   // LDS visibility (queue + qs) before drain

    // Drain: ~160 entries/wave avg -> ~2.5 full-width rounds of tri_merged.
    for (unsigned int base = 0; base < cnt; base += 64) {
        const unsigned int idx = base + (unsigned)lane;
        const bool act = idx < cnt;
        const unsigned int e = act ? queue[wid][idx] : 0u;
        const int f    = (int)(e & 0x3FFFFu);
        const int j    = (int)((e >> 18) & 0xFu);
        const int qloc = wid * 64 + (int)((e >> 22) & 0x3Fu);
        const float QX = qs0[qloc], QY = qs1[qloc], QZ = qs2[qloc];

        if (act) {
            const v4f* rp = (const v4f*)(packed + (size_t)16 * f);
            const v4f r0 = rp[0];
            const v4f r1 = rp[1];
            const v4f r2 = rp[2];
            const float merged = tri_merged(QX, QY, QZ,
                                            r0.x, r0.y, r0.z,
                                            r0.w, r1.x, r1.y,
                                            r1.z, r1.w, r2.x);
            const float am = fabsf(merged);
            const unsigned long long key =
                ((unsigned long long)__float_as_uint(am) << 32)
                | ((unsigned long long)(unsigned)j << 18)
                | (unsigned long long)(unsigned)f;
            atomicMin(&keys[qblock * 256 + qloc], key);
        }
    }
}

// -------- Pass 3: resolve winner -> recompute bit-exact merged, write outs.
__global__ __launch_bounds__(256) void resolve_kernel(
    const float* __restrict__ query_xyz,
    const float* __restrict__ packed,
    const unsigned long long* __restrict__ keys,
    float* __restrict__ out_ret,
    float* __restrict__ out_md,
    int n)
{
    int i = blockIdx.x * blockDim.x + threadIdx.x;
    if (i >= n) return;

    const unsigned long long k = keys[i];
    const int f = (int)(k & 0x3FFFFu);

    const vf3 q = __builtin_nontemporal_load((const vf3*)(query_xyz + 3*i));
    const v4f* rp = (const v4f*)(packed + (size_t)16 * f);
    const v4f r0 = rp[0];
    const v4f r1 = rp[1];
    const v4f r2 = rp[2];
    const float merged = tri_merged(q.x, q.y, q.z,
                                    r0.x, r0.y, r0.z,
                                    r0.w, r1.x, r1.y,
                                    r1.z, r1.w, r2.x);

    __builtin_nontemporal_store((float)f, &out_ret[i]);
    __builtin_nontemporal_store(merged,   &out_md[i]);
}

// -------- Fallback A: R7 one-pass packed main (proven 98us dispatch).
__global__ __launch_bounds__(256) void woot_main_kernel(
    const float* __restrict__ query_xyz,
    const float* __restrict__ packed,
    const int*   __restrict__ cand_ids,
    float*       __restrict__ out_ret,
    float*       __restrict__ out_md,
    int n)
{
    int i = blockIdx.x * blockDim.x + threadIdx.x;
    if (i >= n) return;

    const vf3 q = __builtin_nontemporal_load((const vf3*)(query_xyz + 3*i));
    float best_abs = 0.0f, best_md = 0.0f;
    int best_f = 0;

#pragma unroll 2
    for (int j = 0; j < C_CAND; ++j) {
        const int f = __builtin_nontemporal_load(&cand_ids[i * C_CAND + j]);
        const v4f* rp = (const v4f*)(packed + (size_t)16 * f);
        const v4f r0 = rp[0];
        const v4f r1 = rp[1];
        const v4f r2 = rp[2];
        const float merged = tri_merged(q.x, q.y, q.z,
                                        r0.x, r0.y, r0.z,
                                        r0.w, r1.x, r1.y,
                                        r1.z, r1.w, r2.x);
        const float am = fabsf(merged);
        if (j == 0 || am < best_abs) { best_abs = am; best_md = merged; best_f = f; }
    }

    __builtin_nontemporal_store((float)best_f, &out_ret[i]);
    __builtin_nontemporal_store(best_md,       &out_md[i]);
}

// -------- Fallback B: direct 3-hop kernel (no workspace needed).
__global__ __launch_bounds__(256) void woot_direct_kernel(
    const float* __restrict__ query_xyz,
    const float* __restrict__ temp_verts,
    const int*   __restrict__ faces,
    const int*   __restrict__ cand_ids,
    float*       __restrict__ out_ret,
    float*       __restrict__ out_md,
    int n)
{
    int i = blockIdx.x * blockDim.x + threadIdx.x;
    if (i >= n) return;

    const vf3 q = __builtin_nontemporal_load((const vf3*)(query_xyz + 3*i));
    float best_abs = 0.0f, best_md = 0.0f;
    int best_f = 0;

    for (int j = 0; j < C_CAND; ++j) {
        const int f = __builtin_nontemporal_load(&cand_ids[i * C_CAND + j]);
        const vi3 fi = *(const vi3*)(faces + 3*f);
        const vf3 v0 = *(const vf3*)(temp_verts + 3*fi.x);
        const vf3 v1 = *(const vf3*)(temp_verts + 3*fi.y);
        const vf3 v2 = *(const vf3*)(temp_verts + 3*fi.z);
        const float merged = tri_merged(q.x, q.y, q.z,
                                        v0.x, v0.y, v0.z,
                                        v1.x, v1.y, v1.z,
                                        v2.x, v2.y, v2.z);
        const float am = fabsf(merged);
        if (j == 0 || am < best_abs) { best_abs = am; best_md = merged; best_f = f; }
    }

    __builtin_nontemporal_store((float)best_f, &out_ret[i]);
    __builtin_nontemporal_store(best_md,       &out_md[i]);
}

extern "C" void kernel_launch(void* const* d_in, const int* in_sizes, int n_in,
                              void* d_out, int out_size, void* d_ws, size_t ws_size,
                              hipStream_t stream) {
    const float* query_xyz  = (const float*)d_in[0];
    const float* temp_verts = (const float*)d_in[1];
    const int*   faces      = (const int*)d_in[2];
    const int*   cand_ids   = (const int*)d_in[3];

    const int n = in_sizes[0] / 3;   // N queries
    const int F = in_sizes[2] / 3;   // number of faces

    float* out_ret = (float*)d_out;
    float* out_md  = out_ret + n;

    const int block  = 256;
    const int grid_n = (n + block - 1) / block;
    const int grid_f = (F + block - 1) / block;

    const size_t need_pack   = (size_t)F * 16 * sizeof(float);          // 12.8MB
    const size_t need_sliced = need_pack + (size_t)n * sizeof(unsigned long long);

    if (ws_size >= need_sliced && F < (1 << 18)) {
        float* packed = (float*)d_ws;
        unsigned long long* keys =
            (unsigned long long*)((char*)d_ws + need_pack);
        const int Fs = (F + 3) / 4;

        pack_faces_kernel<<<grid_f, block, 0, stream>>>(
            temp_verts, faces, packed, F);
        fill_keys_kernel<<<grid_n, block, 0, stream>>>(keys, n);
        woot_sliced_kernel<<<grid_n * 4, block, 0, stream>>>(
            query_xyz, packed, cand_ids, keys, n, Fs, F);
        resolve_kernel<<<grid_n, block, 0, stream>>>(
            query_xyz, packed, keys, out_ret, out_md, n);
    } else if (ws_size >= need_pack) {
        float* packed = (float*)d_ws;
        pack_faces_kernel<<<grid_f, block, 0, stream>>>(
            temp_verts, faces, packed, F);
        woot_main_kernel<<<grid_n, block, 0, stream>>>(
            query_xyz, packed, cand_ids, out_ret, out_md, n);
    } else {
        woot_direct_kernel<<<grid_n, block, 0, stream>>>(
            query_xyz, temp_verts, faces, cand_ids, out_ret, out_md, n);
    }
}

// Round 9
// 151.235 us; speedup vs baseline: 1.5603x; 1.5603x over previous
//
#include <hip/hip_runtime.h>
#include <math.h>

#define C_CAND 10
#define SLICE_SHIFT 15              // 32768 faces = 2MB of packed records/slice
#define QCAP 704                    // 63 carry + 640 worst-case one-slice append

typedef float vf3 __attribute__((ext_vector_type(3), aligned(4)));
typedef int   vi3 __attribute__((ext_vector_type(3), aligned(4)));
typedef float v4f __attribute__((ext_vector_type(4)));
typedef int   v2i __attribute__((ext_vector_type(2)));

// Bit-identical point-triangle "merged distance". Op order mirrors numpy
// exactly; contract(off) forbids FMA fusion (IEEE div/sqrt match numpy).
__device__ __forceinline__ float tri_merged(
    float qx, float qy, float qz,
    float v0x, float v0y, float v0z,
    float v1x, float v1y, float v1z,
    float v2x, float v2y, float v2z)
{
#pragma clang fp contract(off)
    const float e10x = v1x - v0x, e10y = v1y - v0y, e10z = v1z - v0z;
    const float e21x = v2x - v1x, e21y = v2y - v1y, e21z = v2z - v1z;
    const float e02x = v0x - v2x, e02y = v0y - v2y, e02z = v0z - v2z;

    const float crx = e10y*e02z - e10z*e02y;
    const float cry = e10z*e02x - e10x*e02z;
    const float crz = e10x*e02y - e10y*e02x;
    const float fNx = -crx, fNy = -cry, fNz = -crz;

    const float a0x = qx - v0x, a0y = qy - v0y, a0z = qz - v0z;
    const float a1x = qx - v1x, a1y = qy - v1y, a1z = qz - v1z;
    const float a2x = qx - v2x, a2y = qy - v2y, a2z = qz - v2z;

    const float num_ab = (a0x*e10x + a0y*e10y) + a0z*e10z;
    const float den_ab = fmaxf((e10x*e10x + e10y*e10y) + e10z*e10z, 1e-9f);
    const float uab = num_ab / den_ab;

    const float num_bc = (a1x*e21x + a1y*e21y) + a1z*e21z;
    const float den_bc = fmaxf((e21x*e21x + e21y*e21y) + e21z*e21z, 1e-9f);
    const float ubc = num_bc / den_bc;

    const float num_ca = (a2x*e02x + a2y*e02y) + a2z*e02z;
    const float den_ca = fmaxf((e02x*e02x + e02y*e02y) + e02z*e02z, 1e-9f);
    const float uca = num_ca / den_ca;

    const bool t1 = (uca > 1.0f) && (uab < 0.0f);
    const bool t2 = (uab > 1.0f) && (ubc < 0.0f);
    const bool t3 = (ubc > 1.0f) && (uca < 0.0f);

    const float c0x = fNy*e10z - fNz*e10y;
    const float c0y = fNz*e10x - fNx*e10z;
    const float c0z = fNx*e10y - fNy*e10x;
    const bool na0 = ((c0x*a0x + c0y*a0y) + c0z*a0z) <= 0.0f;

    const float c1x = fNy*e21z - fNz*e21y;
    const float c1y = fNz*e21x - fNx*e21z;
    const float c1z = fNx*e21y - fNy*e21x;
    const bool na1 = ((c1x*a1x + c1y*a1y) + c1z*a1z) <= 0.0f;

    const float c2x = fNy*e02z - fNz*e02y;
    const float c2y = fNz*e02x - fNx*e02z;
    const float c2z = fNx*e02y - fNy*e02x;
    const bool na2 = ((c2x*a2x + c2y*a2y) + c2z*a2z) <= 0.0f;

    const bool t4 = (uab >= 0.0f) && (uab <= 1.0f) && na0;
    const bool t5 = (ubc >= 0.0f) && (ubc <= 1.0f) && na1 && !t4;
    const bool t6 = (uca >= 0.0f) && (uca <= 1.0f) && na2 && !t4 && !t5;
    const bool t0 = !(t1 || t2 || t3 || t4 || t5 || t6);

    const float nrm = sqrtf((fNx*fNx + fNy*fNy) + fNz*fNz);
    const float dnm = fmaxf(nrm, 1e-9f);
    const float unx = fNx / dnm;
    const float uny = fNy / dnm;
    const float unz = fNz / dnm;

    const float d0 = (a0x*unx + a0y*uny) + a0z*unz;
    const float d1 = sqrtf((a0x*a0x + a0y*a0y) + a0z*a0z);
    const float d2 = sqrtf((a1x*a1x + a1y*a1y) + a1z*a1z);
    const float d3 = sqrtf((a2x*a2x + a2y*a2y) + a2z*a2z);

    const float p4x = v0x + e10x*uab, p4y = v0y + e10y*uab, p4z = v0z + e10z*uab;
    const float p5x = v1x + e21x*ubc, p5y = v1y + e21y*ubc, p5z = v1z + e21z*ubc;
    const float p6x = v2x + e02x*uca, p6y = v2y + e02y*uca, p6z = v2z + e02z*uca;

    const float g4x = qx - p4x, g4y = qy - p4y, g4z = qz - p4z;
    const float g5x = qx - p5x, g5y = qy - p5y, g5z = qz - p5z;
    const float g6x = qx - p6x, g6y = qy - p6y, g6z = qz - p6z;

    const float d4 = sqrtf((g4x*g4x + g4y*g4y) + g4z*g4z);
    const float d5 = sqrtf((g5x*g5x + g5y*g5y) + g5z*g5z);
    const float d6 = sqrtf((g6x*g6x + g6y*g6y) + g6z*g6z);

    float merged = d0 * (t0 ? 1.0f : 0.0f);
    merged = merged + d1 * (t1 ? 1.0f : 0.0f);
    merged = merged + d2 * (t2 ? 1.0f : 0.0f);
    merged = merged + d3 * (t3 ? 1.0f : 0.0f);
    merged = merged + d4 * (t4 ? 1.0f : 0.0f);
    merged = merged + d5 * (t5 ? 1.0f : 0.0f);
    merged = merged + d6 * (t6 ? 1.0f : 0.0f);
    return merged;
}

// -------- Pass 1: pack 9 vertex floats per face into a 64B-stride record.
__global__ __launch_bounds__(256) void pack_faces_kernel(
    const float* __restrict__ temp_verts,
    const int*   __restrict__ faces,
    float*       __restrict__ packed,
    int F)
{
    int t = blockIdx.x * blockDim.x + threadIdx.x;
    if (t >= F) return;

    const vi3 fi = *(const vi3*)(faces + 3*t);
    const vf3 v0 = *(const vf3*)(temp_verts + 3*fi.x);
    const vf3 v1 = *(const vf3*)(temp_verts + 3*fi.y);
    const vf3 v2 = *(const vf3*)(temp_verts + 3*fi.z);

    v4f* dst = (v4f*)(packed + (size_t)16 * t);
    v4f a; a.x = v0.x; a.y = v0.y; a.z = v0.z; a.w = v1.x;
    v4f b; b.x = v1.y; b.y = v1.z; b.z = v2.x; b.w = v2.y;
    v4f c; c.x = v2.z; c.y = 0.0f; c.z = 0.0f; c.w = 0.0f;
    dst[0] = a; dst[1] = b; dst[2] = c;
}

// -------- Pass 2: temporally-sliced gather. All ~1954 blocks are co-resident
// (VGPR<=64, LDS 13.3KB), so a rolled slice loop phases ALL blocks through
// 2MB table windows together -> gathers hit every XCD's L2 (R7: one-hop but
// 0% hit, 316MB misses at 3.2TB/s = the whole 98us). Per-wave LIFO queue w/
// carry-over keeps tri_merged rounds at the ideal count; merge via LDS
// atomicMin(u64) per-wave (R8's GLOBAL atomics wrote 94MB HBM — eliminated).
// Key = |m|_bits<<32 | j<<19 | sign<<18 | f : monotone in |merged|, first-j
// tie-break == np.argmin, sign reconstructs merged bit-exactly (no resolve).
__global__ __launch_bounds__(256) void woot_sliced_kernel(
    const float* __restrict__ query_xyz,
    const float* __restrict__ packed,
    const int*   __restrict__ cand_ids,
    float*       __restrict__ out_ret,
    float*       __restrict__ out_md,
    int n, int NS)
{
    const int tid  = threadIdx.x;
    const int lane = tid & 63;
    const int wid  = tid >> 6;
    const int qi   = blockIdx.x * 256 + tid;
    const bool valid = qi < n;

    __shared__ unsigned int        queue[4][QCAP];
    __shared__ unsigned long long  keys[256];

    // Each wave owns keys[wid*64 .. +63]; no cross-wave access -> no barrier.
    keys[tid] = ~0ull;

    float qx = 0.f, qy = 0.f, qz = 0.f;
    if (valid) {
        const vf3 q = __builtin_nontemporal_load((const vf3*)(query_xyz + 3*qi));
        qx = q.x; qy = q.y; qz = q.z;
    }

    // Candidate ids once (nt streaming), constant-index array -> registers.
    int cid[C_CAND];
    {
        const v2i* cp = (const v2i*)(cand_ids + (size_t)qi * C_CAND);
        v2i c0, c1, c2, c3, c4;
        if (valid) {
            c0 = __builtin_nontemporal_load(cp + 0);
            c1 = __builtin_nontemporal_load(cp + 1);
            c2 = __builtin_nontemporal_load(cp + 2);
            c3 = __builtin_nontemporal_load(cp + 3);
            c4 = __builtin_nontemporal_load(cp + 4);
        } else {
            c0 = c1 = c2 = c3 = c4 = (v2i){-1, -1};
        }
        cid[0]=c0.x; cid[1]=c0.y; cid[2]=c1.x; cid[3]=c1.y; cid[4]=c2.x;
        cid[5]=c2.y; cid[6]=c3.x; cid[7]=c3.y; cid[8]=c4.x; cid[9]=c4.y;
    }

    unsigned int* qw = &queue[wid][0];
    unsigned int cnt = 0;   // wave-uniform queue depth

    for (int s = 0; s < NS; ++s) {
        // Append this slice's candidates (ballot-compacted).
#pragma unroll
        for (int j = 0; j < C_CAND; ++j) {
            const bool in = valid && ((cid[j] >> SLICE_SHIFT) == s);
            const unsigned long long m = __ballot(in);
            if (in) {
                const unsigned long long below = (1ull << lane) - 1ull;
                const unsigned int pos = cnt + (unsigned)__popcll(m & below);
                qw[pos] = (unsigned)cid[j] | ((unsigned)j << 18)
                                           | ((unsigned)lane << 22);
            }
            cnt += (unsigned)__popcll(m);
        }

        // Drain full 64-wide rounds (LIFO top): all records in current/
        // adjacent slice -> L2-warm. Leftover <64 carries to next slice.
        while (cnt >= 64) {
            const unsigned int e = qw[cnt - 64 + lane];
            const int f   = (int)(e & 0x3FFFFu);
            const int j   = (int)((e >> 18) & 0xFu);
            const int src = (int)((e >> 22) & 0x3Fu);
            const float QX = __shfl(qx, src);
            const float QY = __shfl(qy, src);
            const float QZ = __shfl(qz, src);

            const v4f* rp = (const v4f*)(packed + (size_t)16 * f);
            const v4f r0 = rp[0];
            const v4f r1 = rp[1];
            const v4f r2 = rp[2];
            const float merged = tri_merged(QX, QY, QZ,
                                            r0.x, r0.y, r0.z,
                                            r0.w, r1.x, r1.y,
                                            r1.z, r1.w, r2.x);
            const float am = fabsf(merged);
            const unsigned int sign = __float_as_uint(merged) >> 31;
            const unsigned long long key =
                ((unsigned long long)__float_as_uint(am) << 32)
                | ((unsigned long long)(unsigned)j << 19)
                | ((unsigned long long)sign << 18)
                | (unsigned long long)(unsigned)f;
            atomicMin(&keys[wid * 64 + src], key);
            cnt -= 64;
        }
    }

    // Final flush: one masked round (<64 entries).
    if (cnt > 0) {
        const bool act = (unsigned)lane < cnt;
        const unsigned int e = act ? qw[lane] : 0u;
        const int f   = (int)(e & 0x3FFFFu);
        const int j   = (int)((e >> 18) & 0xFu);
        const int src = (int)((e >> 22) & 0x3Fu);
        const float QX = __shfl(qx, src);
        const float QY = __shfl(qy, src);
        const float QZ = __shfl(qz, src);

        if (act) {
            const v4f* rp = (const v4f*)(packed + (size_t)16 * f);
            const v4f r0 = rp[0];
            const v4f r1 = rp[1];
            const v4f r2 = rp[2];
            const float merged = tri_merged(QX, QY, QZ,
                                            r0.x, r0.y, r0.z,
                                            r0.w, r1.x, r1.y,
                                            r1.z, r1.w, r2.x);
            const float am = fabsf(merged);
            const unsigned int sign = __float_as_uint(merged) >> 31;
            const unsigned long long key =
                ((unsigned long long)__float_as_uint(am) << 32)
                | ((unsigned long long)(unsigned)j << 19)
                | ((unsigned long long)sign << 18)
                | (unsigned long long)(unsigned)f;
            atomicMin(&keys[wid * 64 + src], key);
        }
    }

    // Readout (own wave's keys only; LDS atomics retire in program order
    // within the wave, lgkmcnt enforced by compiler).
    if (valid) {
        const unsigned long long k = keys[tid];
        const int f = (int)(k & 0x3FFFFu);
        const unsigned int sign = (unsigned int)((k >> 18) & 1u);
        const unsigned int am_bits = (unsigned int)(k >> 32);
        const float md = __uint_as_float(am_bits | (sign << 31));
        __builtin_nontemporal_store((float)f, &out_ret[qi]);
        __builtin_nontemporal_store(md,       &out_md[qi]);
    }
}

// -------- Fallback: R7 one-pass packed main (proven 98us dispatch).
__global__ __launch_bounds__(256) void woot_main_kernel(
    const float* __restrict__ query_xyz,
    const float* __restrict__ packed,
    const int*   __restrict__ cand_ids,
    float*       __restrict__ out_ret,
    float*       __restrict__ out_md,
    int n)
{
    int i = blockIdx.x * blockDim.x + threadIdx.x;
    if (i >= n) return;

    const vf3 q = __builtin_nontemporal_load((const vf3*)(query_xyz + 3*i));
    float best_abs = 0.0f, best_md = 0.0f;
    int best_f = 0;

#pragma unroll 2
    for (int j = 0; j < C_CAND; ++j) {
        const int f = __builtin_nontemporal_load(&cand_ids[i * C_CAND + j]);
        const v4f* rp = (const v4f*)(packed + (size_t)16 * f);
        const v4f r0 = rp[0];
        const v4f r1 = rp[1];
        const v4f r2 = rp[2];
        const float merged = tri_merged(q.x, q.y, q.z,
                                        r0.x, r0.y, r0.z,
                                        r0.w, r1.x, r1.y,
                                        r1.z, r1.w, r2.x);
        const float am = fabsf(merged);
        if (j == 0 || am < best_abs) { best_abs = am; best_md = merged; best_f = f; }
    }

    __builtin_nontemporal_store((float)best_f, &out_ret[i]);
    __builtin_nontemporal_store(best_md,       &out_md[i]);
}

// -------- Fallback B: direct 3-hop kernel (no workspace needed).
__global__ __launch_bounds__(256) void woot_direct_kernel(
    const float* __restrict__ query_xyz,
    const float* __restrict__ temp_verts,
    const int*   __restrict__ faces,
    const int*   __restrict__ cand_ids,
    float*       __restrict__ out_ret,
    float*       __restrict__ out_md,
    int n)
{
    int i = blockIdx.x * blockDim.x + threadIdx.x;
    if (i >= n) return;

    const vf3 q = __builtin_nontemporal_load((const vf3*)(query_xyz + 3*i));
    float best_abs = 0.0f, best_md = 0.0f;
    int best_f = 0;

    for (int j = 0; j < C_CAND; ++j) {
        const int f = __builtin_nontemporal_load(&cand_ids[i * C_CAND + j]);
        const vi3 fi = *(const vi3*)(faces + 3*f);
        const vf3 v0 = *(const vf3*)(temp_verts + 3*fi.x);
        const vf3 v1 = *(const vf3*)(temp_verts + 3*fi.y);
        const vf3 v2 = *(const vf3*)(temp_verts + 3*fi.z);
        const float merged = tri_merged(q.x, q.y, q.z,
                                        v0.x, v0.y, v0.z,
                                        v1.x, v1.y, v1.z,
                                        v2.x, v2.y, v2.z);
        const float am = fabsf(merged);
        if (j == 0 || am < best_abs) { best_abs = am; best_md = merged; best_f = f; }
    }

    __builtin_nontemporal_store((float)best_f, &out_ret[i]);
    __builtin_nontemporal_store(best_md,       &out_md[i]);
}

extern "C" void kernel_launch(void* const* d_in, const int* in_sizes, int n_in,
                              void* d_out, int out_size, void* d_ws, size_t ws_size,
                              hipStream_t stream) {
    const float* query_xyz  = (const float*)d_in[0];
    const float* temp_verts = (const float*)d_in[1];
    const int*   faces      = (const int*)d_in[2];
    const int*   cand_ids   = (const int*)d_in[3];

    const int n = in_sizes[0] / 3;   // N queries
    const int F = in_sizes[2] / 3;   // number of faces

    float* out_ret = (float*)d_out;
    float* out_md  = out_ret + n;

    const int block  = 256;
    const int grid_n = (n + block - 1) / block;
    const int grid_f = (F + block - 1) / block;

    const size_t need_pack = (size_t)F * 16 * sizeof(float);  // 12.8MB

    if (ws_size >= need_pack && F <= (1 << 18)) {
        float* packed = (float*)d_ws;
        const int NS = (F + (1 << SLICE_SHIFT) - 1) >> SLICE_SHIFT;
        pack_faces_kernel<<<grid_f, block, 0, stream>>>(
            temp_verts, faces, packed, F);
        woot_sliced_kernel<<<grid_n, block, 0, stream>>>(
            query_xyz, packed, cand_ids, out_ret, out_md, n, NS);
    } else if (ws_size >= need_pack) {
        float* packed = (float*)d_ws;
        pack_faces_kernel<<<grid_f, block, 0, stream>>>(
            temp_verts, faces, packed, F);
        woot_main_kernel<<<grid_n, block, 0, stream>>>(
            query_xyz, packed, cand_ids, out_ret, out_md, n);
    } else {
        woot_direct_kernel<<<grid_n, block, 0, stream>>>(
            query_xyz, temp_verts, faces, cand_ids, out_ret, out_md, n);
    }
}

// Round 10
// 145.144 us; speedup vs baseline: 1.6258x; 1.0420x over previous
//
#include <hip/hip_runtime.h>
#include <math.h>

#define C_CAND 10
#define SLICE_SHIFT 15              // 32768 faces = 2MB of packed records/slice
#define QCAP 704                    // 63 carry + 640 worst-case one-slice append

typedef float vf3 __attribute__((ext_vector_type(3), aligned(4)));
typedef int   vi3 __attribute__((ext_vector_type(3), aligned(4)));
typedef float v4f __attribute__((ext_vector_type(4)));
typedef int   v2i __attribute__((ext_vector_type(2)));

// Per-candidate merged distance using PER-FACE PRECOMPUTED unit_n and
// clamped edge-length denominators (bit-identical: pack pass computes them
// with numpy's exact op order; division num/den here uses the same bits
// numpy divides by). contract(off) forbids FMA fusion throughout.
__device__ __forceinline__ float tri_merged_pre(
    float qx, float qy, float qz,
    float v0x, float v0y, float v0z,
    float v1x, float v1y, float v1z,
    float v2x, float v2y, float v2z,
    float unx, float uny, float unz,
    float dab, float dbc, float dca)
{
#pragma clang fp contract(off)
    const float e10x = v1x - v0x, e10y = v1y - v0y, e10z = v1z - v0z;
    const float e21x = v2x - v1x, e21y = v2y - v1y, e21z = v2z - v1z;
    const float e02x = v0x - v2x, e02y = v0y - v2y, e02z = v0z - v2z;

    // fN = -cross(e10, e02)  (needed for the c0/c1/c2 crosses)
    const float crx = e10y*e02z - e10z*e02y;
    const float cry = e10z*e02x - e10x*e02z;
    const float crz = e10x*e02y - e10y*e02x;
    const float fNx = -crx, fNy = -cry, fNz = -crz;

    const float a0x = qx - v0x, a0y = qy - v0y, a0z = qz - v0z;
    const float a1x = qx - v1x, a1y = qy - v1y, a1z = qz - v1z;
    const float a2x = qx - v2x, a2y = qy - v2y, a2z = qz - v2z;

    const float num_ab = (a0x*e10x + a0y*e10y) + a0z*e10z;
    const float uab = num_ab / dab;

    const float num_bc = (a1x*e21x + a1y*e21y) + a1z*e21z;
    const float ubc = num_bc / dbc;

    const float num_ca = (a2x*e02x + a2y*e02y) + a2z*e02z;
    const float uca = num_ca / dca;

    const bool t1 = (uca > 1.0f) && (uab < 0.0f);
    const bool t2 = (uab > 1.0f) && (ubc < 0.0f);
    const bool t3 = (ubc > 1.0f) && (uca < 0.0f);

    const float c0x = fNy*e10z - fNz*e10y;
    const float c0y = fNz*e10x - fNx*e10z;
    const float c0z = fNx*e10y - fNy*e10x;
    const bool na0 = ((c0x*a0x + c0y*a0y) + c0z*a0z) <= 0.0f;

    const float c1x = fNy*e21z - fNz*e21y;
    const float c1y = fNz*e21x - fNx*e21z;
    const float c1z = fNx*e21y - fNy*e21x;
    const bool na1 = ((c1x*a1x + c1y*a1y) + c1z*a1z) <= 0.0f;

    const float c2x = fNy*e02z - fNz*e02y;
    const float c2y = fNz*e02x - fNx*e02z;
    const float c2z = fNx*e02y - fNy*e02x;
    const bool na2 = ((c2x*a2x + c2y*a2y) + c2z*a2z) <= 0.0f;

    const bool t4 = (uab >= 0.0f) && (uab <= 1.0f) && na0;
    const bool t5 = (ubc >= 0.0f) && (ubc <= 1.0f) && na1 && !t4;
    const bool t6 = (uca >= 0.0f) && (uca <= 1.0f) && na2 && !t4 && !t5;
    const bool t0 = !(t1 || t2 || t3 || t4 || t5 || t6);

    const float d0 = (a0x*unx + a0y*uny) + a0z*unz;
    const float d1 = sqrtf((a0x*a0x + a0y*a0y) + a0z*a0z);
    const float d2 = sqrtf((a1x*a1x + a1y*a1y) + a1z*a1z);
    const float d3 = sqrtf((a2x*a2x + a2y*a2y) + a2z*a2z);

    const float p4x = v0x + e10x*uab, p4y = v0y + e10y*uab, p4z = v0z + e10z*uab;
    const float p5x = v1x + e21x*ubc, p5y = v1y + e21y*ubc, p5z = v1z + e21z*ubc;
    const float p6x = v2x + e02x*uca, p6y = v2y + e02y*uca, p6z = v2z + e02z*uca;

    const float g4x = qx - p4x, g4y = qy - p4y, g4z = qz - p4z;
    const float g5x = qx - p5x, g5y = qy - p5y, g5z = qz - p5z;
    const float g6x = qx - p6x, g6y = qy - p6y, g6z = qz - p6z;

    const float d4 = sqrtf((g4x*g4x + g4y*g4y) + g4z*g4z);
    const float d5 = sqrtf((g5x*g5x + g5y*g5y) + g5z*g5z);
    const float d6 = sqrtf((g6x*g6x + g6y*g6y) + g6z*g6z);

    float merged = d0 * (t0 ? 1.0f : 0.0f);
    merged = merged + d1 * (t1 ? 1.0f : 0.0f);
    merged = merged + d2 * (t2 ? 1.0f : 0.0f);
    merged = merged + d3 * (t3 ? 1.0f : 0.0f);
    merged = merged + d4 * (t4 ? 1.0f : 0.0f);
    merged = merged + d5 * (t5 ? 1.0f : 0.0f);
    merged = merged + d6 * (t6 ? 1.0f : 0.0f);
    return merged;
}

// Full per-candidate version (fallback B only).
__device__ __forceinline__ float tri_merged_full(
    float qx, float qy, float qz,
    float v0x, float v0y, float v0z,
    float v1x, float v1y, float v1z,
    float v2x, float v2y, float v2z)
{
#pragma clang fp contract(off)
    const float e10x = v1x - v0x, e10y = v1y - v0y, e10z = v1z - v0z;
    const float e21x = v2x - v1x, e21y = v2y - v1y, e21z = v2z - v1z;
    const float e02x = v0x - v2x, e02y = v0y - v2y, e02z = v0z - v2z;
    const float dab = fmaxf((e10x*e10x + e10y*e10y) + e10z*e10z, 1e-9f);
    const float dbc = fmaxf((e21x*e21x + e21y*e21y) + e21z*e21z, 1e-9f);
    const float dca = fmaxf((e02x*e02x + e02y*e02y) + e02z*e02z, 1e-9f);
    const float crx = e10y*e02z - e10z*e02y;
    const float cry = e10z*e02x - e10x*e02z;
    const float crz = e10x*e02y - e10y*e02x;
    const float fNx = -crx, fNy = -cry, fNz = -crz;
    const float nrm = sqrtf((fNx*fNx + fNy*fNy) + fNz*fNz);
    const float dnm = fmaxf(nrm, 1e-9f);
    const float unx = fNx / dnm;
    const float uny = fNy / dnm;
    const float unz = fNz / dnm;
    return tri_merged_pre(qx, qy, qz, v0x, v0y, v0z, v1x, v1y, v1z,
                          v2x, v2y, v2z, unx, uny, unz, dab, dbc, dca);
}

// -------- Pass 1: pack per-face record (64B):
//   r0: v0x v0y v0z v1x | r1: v1y v1z v2x v2y
//   r2: v2z unx uny unz | r3: dab dbc dca pad
// Moves 3 IEEE divides + 1 sqrt + 4 dots + maxes per CANDIDATE (x25 reuse)
// into a once-per-FACE pass. Op order mirrors numpy exactly; contract off.
__global__ __launch_bounds__(256) void pack_faces_kernel(
    const float* __restrict__ temp_verts,
    const int*   __restrict__ faces,
    float*       __restrict__ packed,
    int F)
{
#pragma clang fp contract(off)
    int t = blockIdx.x * blockDim.x + threadIdx.x;
    if (t >= F) return;

    const vi3 fi = *(const vi3*)(faces + 3*t);
    const vf3 v0 = *(const vf3*)(temp_verts + 3*fi.x);
    const vf3 v1 = *(const vf3*)(temp_verts + 3*fi.y);
    const vf3 v2 = *(const vf3*)(temp_verts + 3*fi.z);

    const float e10x = v1.x - v0.x, e10y = v1.y - v0.y, e10z = v1.z - v0.z;
    const float e21x = v2.x - v1.x, e21y = v2.y - v1.y, e21z = v2.z - v1.z;
    const float e02x = v0.x - v2.x, e02y = v0.y - v2.y, e02z = v0.z - v2.z;

    const float dab = fmaxf((e10x*e10x + e10y*e10y) + e10z*e10z, 1e-9f);
    const float dbc = fmaxf((e21x*e21x + e21y*e21y) + e21z*e21z, 1e-9f);
    const float dca = fmaxf((e02x*e02x + e02y*e02y) + e02z*e02z, 1e-9f);

    const float crx = e10y*e02z - e10z*e02y;
    const float cry = e10z*e02x - e10x*e02z;
    const float crz = e10x*e02y - e10y*e02x;
    const float fNx = -crx, fNy = -cry, fNz = -crz;
    const float nrm = sqrtf((fNx*fNx + fNy*fNy) + fNz*fNz);
    const float dnm = fmaxf(nrm, 1e-9f);
    const float unx = fNx / dnm;
    const float uny = fNy / dnm;
    const float unz = fNz / dnm;

    v4f* dst = (v4f*)(packed + (size_t)16 * t);
    v4f a; a.x = v0.x; a.y = v0.y; a.z = v0.z; a.w = v1.x;
    v4f b; b.x = v1.y; b.y = v1.z; b.z = v2.x; b.w = v2.y;
    v4f c; c.x = v2.z; c.y = unx;  c.z = uny;  c.w = unz;
    v4f d; d.x = dab;  d.y = dbc;  d.z = dca;  d.w = 0.0f;
    dst[0] = a; dst[1] = b; dst[2] = c; dst[3] = d;
}

// -------- Pass 2: temporally-sliced gather (R9 structure, proven 98->77us).
// All ~1954 blocks co-resident -> rolled slice loop phases every block
// through 2MB table windows together -> gathers L2-hit on every XCD.
// Per-wave LIFO queue w/ carry; merge via LDS atomicMin(u64) per wave.
// Key = |m|_bits<<32 | j<<19 | sign<<18 | f.
__global__ __launch_bounds__(256) void woot_sliced_kernel(
    const float* __restrict__ query_xyz,
    const float* __restrict__ packed,
    const int*   __restrict__ cand_ids,
    float*       __restrict__ out_ret,
    float*       __restrict__ out_md,
    int n, int NS)
{
    const int tid  = threadIdx.x;
    const int lane = tid & 63;
    const int wid  = tid >> 6;
    const int qi   = blockIdx.x * 256 + tid;
    const bool valid = qi < n;

    __shared__ unsigned int        queue[4][QCAP];
    __shared__ unsigned long long  keys[256];

    keys[tid] = ~0ull;   // wave-private range; no cross-wave access

    float qx = 0.f, qy = 0.f, qz = 0.f;
    if (valid) {
        const vf3 q = __builtin_nontemporal_load((const vf3*)(query_xyz + 3*qi));
        qx = q.x; qy = q.y; qz = q.z;
    }

    int cid[C_CAND];
    {
        const v2i* cp = (const v2i*)(cand_ids + (size_t)qi * C_CAND);
        v2i c0, c1, c2, c3, c4;
        if (valid) {
            c0 = __builtin_nontemporal_load(cp + 0);
            c1 = __builtin_nontemporal_load(cp + 1);
            c2 = __builtin_nontemporal_load(cp + 2);
            c3 = __builtin_nontemporal_load(cp + 3);
            c4 = __builtin_nontemporal_load(cp + 4);
        } else {
            c0 = c1 = c2 = c3 = c4 = (v2i){-1, -1};
        }
        cid[0]=c0.x; cid[1]=c0.y; cid[2]=c1.x; cid[3]=c1.y; cid[4]=c2.x;
        cid[5]=c2.y; cid[6]=c3.x; cid[7]=c3.y; cid[8]=c4.x; cid[9]=c4.y;
    }

    unsigned int* qw = &queue[wid][0];
    unsigned int cnt = 0;

    for (int s = 0; s < NS; ++s) {
#pragma unroll
        for (int j = 0; j < C_CAND; ++j) {
            const bool in = valid && ((cid[j] >> SLICE_SHIFT) == s);
            const unsigned long long m = __ballot(in);
            if (in) {
                const unsigned long long below = (1ull << lane) - 1ull;
                const unsigned int pos = cnt + (unsigned)__popcll(m & below);
                qw[pos] = (unsigned)cid[j] | ((unsigned)j << 18)
                                           | ((unsigned)lane << 22);
            }
            cnt += (unsigned)__popcll(m);
        }

        while (cnt >= 64) {
            const unsigned int e = qw[cnt - 64 + lane];
            const int f   = (int)(e & 0x3FFFFu);
            const int j   = (int)((e >> 18) & 0xFu);
            const int src = (int)((e >> 22) & 0x3Fu);
            const float QX = __shfl(qx, src);
            const float QY = __shfl(qy, src);
            const float QZ = __shfl(qz, src);

            const v4f* rp = (const v4f*)(packed + (size_t)16 * f);
            const v4f r0 = rp[0];
            const v4f r1 = rp[1];
            const v4f r2 = rp[2];
            const v4f r3 = rp[3];
            const float merged = tri_merged_pre(QX, QY, QZ,
                                                r0.x, r0.y, r0.z,
                                                r0.w, r1.x, r1.y,
                                                r1.z, r1.w, r2.x,
                                                r2.y, r2.z, r2.w,
                                                r3.x, r3.y, r3.z);
            const float am = fabsf(merged);
            const unsigned int sign = __float_as_uint(merged) >> 31;
            const unsigned long long key =
                ((unsigned long long)__float_as_uint(am) << 32)
                | ((unsigned long long)(unsigned)j << 19)
                | ((unsigned long long)sign << 18)
                | (unsigned long long)(unsigned)f;
            atomicMin(&keys[wid * 64 + src], key);
            cnt -= 64;
        }
    }

    if (cnt > 0) {
        const bool act = (unsigned)lane < cnt;
        const unsigned int e = act ? qw[lane] : 0u;
        const int f   = (int)(e & 0x3FFFFu);
        const int j   = (int)((e >> 18) & 0xFu);
        const int src = (int)((e >> 22) & 0x3Fu);
        const float QX = __shfl(qx, src);
        const float QY = __shfl(qy, src);
        const float QZ = __shfl(qz, src);

        if (act) {
            const v4f* rp = (const v4f*)(packed + (size_t)16 * f);
            const v4f r0 = rp[0];
            const v4f r1 = rp[1];
            const v4f r2 = rp[2];
            const v4f r3 = rp[3];
            const float merged = tri_merged_pre(QX, QY, QZ,
                                                r0.x, r0.y, r0.z,
                                                r0.w, r1.x, r1.y,
                                                r1.z, r1.w, r2.x,
                                                r2.y, r2.z, r2.w,
                                                r3.x, r3.y, r3.z);
            const float am = fabsf(merged);
            const unsigned int sign = __float_as_uint(merged) >> 31;
            const unsigned long long key =
                ((unsigned long long)__float_as_uint(am) << 32)
                | ((unsigned long long)(unsigned)j << 19)
                | ((unsigned long long)sign << 18)
                | (unsigned long long)(unsigned)f;
            atomicMin(&keys[wid * 64 + src], key);
        }
    }

    if (valid) {
        const unsigned long long k = keys[tid];
        const int f = (int)(k & 0x3FFFFu);
        const unsigned int sign = (unsigned int)((k >> 18) & 1u);
        const unsigned int am_bits = (unsigned int)(k >> 32);
        const float md = __uint_as_float(am_bits | (sign << 31));
        __builtin_nontemporal_store((float)f, &out_ret[qi]);
        __builtin_nontemporal_store(md,       &out_md[qi]);
    }
}

// -------- Fallback A: one-pass packed main (new record layout).
__global__ __launch_bounds__(256) void woot_main_kernel(
    const float* __restrict__ query_xyz,
    const float* __restrict__ packed,
    const int*   __restrict__ cand_ids,
    float*       __restrict__ out_ret,
    float*       __restrict__ out_md,
    int n)
{
    int i = blockIdx.x * blockDim.x + threadIdx.x;
    if (i >= n) return;

    const vf3 q = __builtin_nontemporal_load((const vf3*)(query_xyz + 3*i));
    float best_abs = 0.0f, best_md = 0.0f;
    int best_f = 0;

#pragma unroll 2
    for (int j = 0; j < C_CAND; ++j) {
        const int f = __builtin_nontemporal_load(&cand_ids[i * C_CAND + j]);
        const v4f* rp = (const v4f*)(packed + (size_t)16 * f);
        const v4f r0 = rp[0];
        const v4f r1 = rp[1];
        const v4f r2 = rp[2];
        const v4f r3 = rp[3];
        const float merged = tri_merged_pre(q.x, q.y, q.z,
                                            r0.x, r0.y, r0.z,
                                            r0.w, r1.x, r1.y,
                                            r1.z, r1.w, r2.x,
                                            r2.y, r2.z, r2.w,
                                            r3.x, r3.y, r3.z);
        const float am = fabsf(merged);
        if (j == 0 || am < best_abs) { best_abs = am; best_md = merged; best_f = f; }
    }

    __builtin_nontemporal_store((float)best_f, &out_ret[i]);
    __builtin_nontemporal_store(best_md,       &out_md[i]);
}

// -------- Fallback B: direct 3-hop kernel (no workspace needed).
__global__ __launch_bounds__(256) void woot_direct_kernel(
    const float* __restrict__ query_xyz,
    const float* __restrict__ temp_verts,
    const int*   __restrict__ faces,
    const int*   __restrict__ cand_ids,
    float*       __restrict__ out_ret,
    float*       __restrict__ out_md,
    int n)
{
    int i = blockIdx.x * blockDim.x + threadIdx.x;
    if (i >= n) return;

    const vf3 q = __builtin_nontemporal_load((const vf3*)(query_xyz + 3*i));
    float best_abs = 0.0f, best_md = 0.0f;
    int best_f = 0;

    for (int j = 0; j < C_CAND; ++j) {
        const int f = __builtin_nontemporal_load(&cand_ids[i * C_CAND + j]);
        const vi3 fi = *(const vi3*)(faces + 3*f);
        const vf3 v0 = *(const vf3*)(temp_verts + 3*fi.x);
        const vf3 v1 = *(const vf3*)(temp_verts + 3*fi.y);
        const vf3 v2 = *(const vf3*)(temp_verts + 3*fi.z);
        const float merged = tri_merged_full(q.x, q.y, q.z,
                                             v0.x, v0.y, v0.z,
                                             v1.x, v1.y, v1.z,
                                             v2.x, v2.y, v2.z);
        const float am = fabsf(merged);
        if (j == 0 || am < best_abs) { best_abs = am; best_md = merged; best_f = f; }
    }

    __builtin_nontemporal_store((float)best_f, &out_ret[i]);
    __builtin_nontemporal_store(best_md,       &out_md[i]);
}

extern "C" void kernel_launch(void* const* d_in, const int* in_sizes, int n_in,
                              void* d_out, int out_size, void* d_ws, size_t ws_size,
                              hipStream_t stream) {
    const float* query_xyz  = (const float*)d_in[0];
    const float* temp_verts = (const float*)d_in[1];
    const int*   faces      = (const int*)d_in[2];
    const int*   cand_ids   = (const int*)d_in[3];

    const int n = in_sizes[0] / 3;   // N queries
    const int F = in_sizes[2] / 3;   // number of faces

    float* out_ret = (float*)d_out;
    float* out_md  = out_ret + n;

    const int block  = 256;
    const int grid_n = (n + block - 1) / block;
    const int grid_f = (F + block - 1) / block;

    const size_t need_pack = (size_t)F * 16 * sizeof(float);  // 12.8MB

    if (ws_size >= need_pack && F <= (1 << 18)) {
        float* packed = (float*)d_ws;
        const int NS = (F + (1 << SLICE_SHIFT) - 1) >> SLICE_SHIFT;
        pack_faces_kernel<<<grid_f, block, 0, stream>>>(
            temp_verts, faces, packed, F);
        woot_sliced_kernel<<<grid_n, block, 0, stream>>>(
            query_xyz, packed, cand_ids, out_ret, out_md, n, NS);
    } else if (ws_size >= need_pack) {
        float* packed = (float*)d_ws;
        pack_faces_kernel<<<grid_f, block, 0, stream>>>(
            temp_verts, faces, packed, F);
        woot_main_kernel<<<grid_n, block, 0, stream>>>(
            query_xyz, packed, cand_ids, out_ret, out_md, n);
    } else {
        woot_direct_kernel<<<grid_n, block, 0, stream>>>(
            query_xyz, temp_verts, faces, cand_ids, out_ret, out_md, n);
    }
}

// Round 12
// 143.989 us; speedup vs baseline: 1.6389x; 1.0080x over previous
//
#include <hip/hip_runtime.h>
#include <math.h>

#define C_CAND 10
#define SLICE_SHIFT 15              // 32768 faces = 2MB of packed records/slice
#define QCAP 704                    // 63 carry + 640 worst-case one-slice append

typedef float vf3 __attribute__((ext_vector_type(3), aligned(4)));
typedef int   vi3 __attribute__((ext_vector_type(3), aligned(4)));
typedef float v4f __attribute__((ext_vector_type(4)));
typedef int   v2i __attribute__((ext_vector_type(2)));

// Per-candidate merged distance using PER-FACE PRECOMPUTED unit_n and
// clamped edge-length denominators (bit-identical: pack pass computes them
// with numpy's exact op order; division num/den here uses the same bits
// numpy divides by). contract(off) forbids FMA fusion.
__device__ __forceinline__ float tri_merged_pre(
    float qx, float qy, float qz,
    float v0x, float v0y, float v0z,
    float v1x, float v1y, float v1z,
    float v2x, float v2y, float v2z,
    float unx, float uny, float unz,
    float dab, float dbc, float dca)
{
#pragma clang fp contract(off)
    const float e10x = v1x - v0x, e10y = v1y - v0y, e10z = v1z - v0z;
    const float e21x = v2x - v1x, e21y = v2y - v1y, e21z = v2z - v1z;
    const float e02x = v0x - v2x, e02y = v0y - v2y, e02z = v0z - v2z;

    // fN = -cross(e10, e02)  (needed for the c0/c1/c2 crosses)
    const float crx = e10y*e02z - e10z*e02y;
    const float cry = e10z*e02x - e10x*e02z;
    const float crz = e10x*e02y - e10y*e02x;
    const float fNx = -crx, fNy = -cry, fNz = -crz;

    const float a0x = qx - v0x, a0y = qy - v0y, a0z = qz - v0z;
    const float a1x = qx - v1x, a1y = qy - v1y, a1z = qz - v1z;
    const float a2x = qx - v2x, a2y = qy - v2y, a2z = qz - v2z;

    const float num_ab = (a0x*e10x + a0y*e10y) + a0z*e10z;
    const float uab = num_ab / dab;

    const float num_bc = (a1x*e21x + a1y*e21y) + a1z*e21z;
    const float ubc = num_bc / dbc;

    const float num_ca = (a2x*e02x + a2y*e02y) + a2z*e02z;
    const float uca = num_ca / dca;

    const bool t1 = (uca > 1.0f) && (uab < 0.0f);
    const bool t2 = (uab > 1.0f) && (ubc < 0.0f);
    const bool t3 = (ubc > 1.0f) && (uca < 0.0f);

    const float c0x = fNy*e10z - fNz*e10y;
    const float c0y = fNz*e10x - fNx*e10z;
    const float c0z = fNx*e10y - fNy*e10x;
    const bool na0 = ((c0x*a0x + c0y*a0y) + c0z*a0z) <= 0.0f;

    const float c1x = fNy*e21z - fNz*e21y;
    const float c1y = fNz*e21x - fNx*e21z;
    const float c1z = fNx*e21y - fNy*e21x;
    const bool na1 = ((c1x*a1x + c1y*a1y) + c1z*a1z) <= 0.0f;

    const float c2x = fNy*e02z - fNz*e02y;
    const float c2y = fNz*e02x - fNx*e02z;
    const float c2z = fNx*e02y - fNy*e02x;
    const bool na2 = ((c2x*a2x + c2y*a2y) + c2z*a2z) <= 0.0f;

    const bool t4 = (uab >= 0.0f) && (uab <= 1.0f) && na0;
    const bool t5 = (ubc >= 0.0f) && (ubc <= 1.0f) && na1 && !t4;
    const bool t6 = (uca >= 0.0f) && (uca <= 1.0f) && na2 && !t4 && !t5;
    const bool t0 = !(t1 || t2 || t3 || t4 || t5 || t6);

    const float d0 = (a0x*unx + a0y*uny) + a0z*unz;
    const float d1 = sqrtf((a0x*a0x + a0y*a0y) + a0z*a0z);
    const float d2 = sqrtf((a1x*a1x + a1y*a1y) + a1z*a1z);
    const float d3 = sqrtf((a2x*a2x + a2y*a2y) + a2z*a2z);

    const float p4x = v0x + e10x*uab, p4y = v0y + e10y*uab, p4z = v0z + e10z*uab;
    const float p5x = v1x + e21x*ubc, p5y = v1y + e21y*ubc, p5z = v1z + e21z*ubc;
    const float p6x = v2x + e02x*uca, p6y = v2y + e02y*uca, p6z = v2z + e02z*uca;

    const float g4x = qx - p4x, g4y = qy - p4y, g4z = qz - p4z;
    const float g5x = qx - p5x, g5y = qy - p5y, g5z = qz - p5z;
    const float g6x = qx - p6x, g6y = qy - p6y, g6z = qz - p6z;

    const float d4 = sqrtf((g4x*g4x + g4y*g4y) + g4z*g4z);
    const float d5 = sqrtf((g5x*g5x + g5y*g5y) + g5z*g5z);
    const float d6 = sqrtf((g6x*g6x + g6y*g6y) + g6z*g6z);

    float merged = d0 * (t0 ? 1.0f : 0.0f);
    merged = merged + d1 * (t1 ? 1.0f : 0.0f);
    merged = merged + d2 * (t2 ? 1.0f : 0.0f);
    merged = merged + d3 * (t3 ? 1.0f : 0.0f);
    merged = merged + d4 * (t4 ? 1.0f : 0.0f);
    merged = merged + d5 * (t5 ? 1.0f : 0.0f);
    merged = merged + d6 * (t6 ? 1.0f : 0.0f);
    return merged;
}

// Full per-candidate version (fallback B only).
__device__ __forceinline__ float tri_merged_full(
    float qx, float qy, float qz,
    float v0x, float v0y, float v0z,
    float v1x, float v1y, float v1z,
    float v2x, float v2y, float v2z)
{
#pragma clang fp contract(off)
    const float e10x = v1x - v0x, e10y = v1y - v0y, e10z = v1z - v0z;
    const float e21x = v2x - v1x, e21y = v2y - v1y, e21z = v2z - v1z;
    const float e02x = v0x - v2x, e02y = v0y - v2y, e02z = v0z - v2z;
    const float dab = fmaxf((e10x*e10x + e10y*e10y) + e10z*e10z, 1e-9f);
    const float dbc = fmaxf((e21x*e21x + e21y*e21y) + e21z*e21z, 1e-9f);
    const float dca = fmaxf((e02x*e02x + e02y*e02y) + e02z*e02z, 1e-9f);
    const float crx = e10y*e02z - e10z*e02y;
    const float cry = e10z*e02x - e10x*e02z;
    const float crz = e10x*e02y - e10y*e02x;
    const float fNx = -crx, fNy = -cry, fNz = -crz;
    const float nrm = sqrtf((fNx*fNx + fNy*fNy) + fNz*fNz);
    const float dnm = fmaxf(nrm, 1e-9f);
    const float unx = fNx / dnm;
    const float uny = fNy / dnm;
    const float unz = fNz / dnm;
    return tri_merged_pre(qx, qy, qz, v0x, v0y, v0z, v1x, v1y, v1z,
                          v2x, v2y, v2z, unx, uny, unz, dab, dbc, dca);
}

// -------- Pass 1: pack per-face record (64B):
//   r0: v0x v0y v0z v1x | r1: v1y v1z v2x v2y
//   r2: v2z unx uny unz | r3: dab dbc dca pad
// Moves 3 IEEE divides + 1 sqrt + 4 dots + maxes per CANDIDATE (x25 reuse)
// into a once-per-FACE pass. Op order mirrors numpy exactly; contract off.
__global__ __launch_bounds__(256) void pack_faces_kernel(
    const float* __restrict__ temp_verts,
    const int*   __restrict__ faces,
    float*       __restrict__ packed,
    int F)
{
#pragma clang fp contract(off)
    int t = blockIdx.x * blockDim.x + threadIdx.x;
    if (t >= F) return;

    const vi3 fi = *(const vi3*)(faces + 3*t);
    const vf3 v0 = *(const vf3*)(temp_verts + 3*fi.x);
    const vf3 v1 = *(const vf3*)(temp_verts + 3*fi.y);
    const vf3 v2 = *(const vf3*)(temp_verts + 3*fi.z);

    const float e10x = v1.x - v0.x, e10y = v1.y - v0.y, e10z = v1.z - v0.z;
    const float e21x = v2.x - v1.x, e21y = v2.y - v1.y, e21z = v2.z - v1.z;
    const float e02x = v0.x - v2.x, e02y = v0.y - v2.y, e02z = v0.z - v2.z;

    const float dab = fmaxf((e10x*e10x + e10y*e10y) + e10z*e10z, 1e-9f);
    const float dbc = fmaxf((e21x*e21x + e21y*e21y) + e21z*e21z, 1e-9f);
    const float dca = fmaxf((e02x*e02x + e02y*e02y) + e02z*e02z, 1e-9f);

    const float crx = e10y*e02z - e10z*e02y;
    const float cry = e10z*e02x - e10x*e02z;
    const float crz = e10x*e02y - e10y*e02x;
    const float fNx = -crx, fNy = -cry, fNz = -crz;
    const float nrm = sqrtf((fNx*fNx + fNy*fNy) + fNz*fNz);
    const float dnm = fmaxf(nrm, 1e-9f);
    const float unx = fNx / dnm;
    const float uny = fNy / dnm;
    const float unz = fNz / dnm;

    v4f* dst = (v4f*)(packed + (size_t)16 * t);
    v4f a; a.x = v0.x; a.y = v0.y; a.z = v0.z; a.w = v1.x;
    v4f b; b.x = v1.y; b.y = v1.z; b.z = v2.x; b.w = v2.y;
    v4f c; c.x = v2.z; c.y = unx;  c.z = uny;  c.w = unz;
    v4f d; d.x = dab;  d.y = dbc;  d.z = dca;  d.w = 0.0f;
    dst[0] = a; dst[1] = b; dst[2] = c; dst[3] = d;
}

// -------- Pass 2: temporally-sliced gather (R9 structure, proven 98->77us).
// All ~1954 blocks co-resident -> rolled slice loop phases every block
// through 2MB table windows together -> gathers L2-hit on every XCD.
// Per-wave LIFO queue w/ carry; merge via LDS atomicMin(u64) per wave.
// Key = |m|_bits<<32 | j<<19 | sign<<18 | f.
__global__ __launch_bounds__(256) void woot_sliced_kernel(
    const float* __restrict__ query_xyz,
    const float* __restrict__ packed,
    const int*   __restrict__ cand_ids,
    float*       __restrict__ out_ret,
    float*       __restrict__ out_md,
    int n, int NS)
{
    const int tid  = threadIdx.x;
    const int lane = tid & 63;
    const int wid  = tid >> 6;
    const int qi   = blockIdx.x * 256 + tid;
    const bool valid = qi < n;

    __shared__ unsigned int        queue[4][QCAP];
    __shared__ unsigned long long  keys[256];

    keys[tid] = ~0ull;   // wave-private range; no cross-wave access

    float qx = 0.f, qy = 0.f, qz = 0.f;
    if (valid) {
        const vf3 q = __builtin_nontemporal_load((const vf3*)(query_xyz + 3*qi));
        qx = q.x; qy = q.y; qz = q.z;
    }

    int cid[C_CAND];
    {
        const v2i* cp = (const v2i*)(cand_ids + (size_t)qi * C_CAND);
        v2i c0, c1, c2, c3, c4;
        if (valid) {
            c0 = __builtin_nontemporal_load(cp + 0);
            c1 = __builtin_nontemporal_load(cp + 1);
            c2 = __builtin_nontemporal_load(cp + 2);
            c3 = __builtin_nontemporal_load(cp + 3);
            c4 = __builtin_nontemporal_load(cp + 4);
        } else {
            c0 = c1 = c2 = c3 = c4 = (v2i){-1, -1};
        }
        cid[0]=c0.x; cid[1]=c0.y; cid[2]=c1.x; cid[3]=c1.y; cid[4]=c2.x;
        cid[5]=c2.y; cid[6]=c3.x; cid[7]=c3.y; cid[8]=c4.x; cid[9]=c4.y;
    }

    unsigned int* qw = &queue[wid][0];
    unsigned int cnt = 0;

    for (int s = 0; s < NS; ++s) {
#pragma unroll
        for (int j = 0; j < C_CAND; ++j) {
            const bool in = valid && ((cid[j] >> SLICE_SHIFT) == s);
            const unsigned long long m = __ballot(in);
            if (in) {
                const unsigned long long below = (1ull << lane) - 1ull;
                const unsigned int pos = cnt + (unsigned)__popcll(m & below);
                qw[pos] = (unsigned)cid[j] | ((unsigned)j << 18)
                                           | ((unsigned)lane << 22);
            }
            cnt += (unsigned)__popcll(m);
        }

        while (cnt >= 64) {
            const unsigned int e = qw[cnt - 64 + lane];
            const int f   = (int)(e & 0x3FFFFu);
            const int j   = (int)((e >> 18) & 0xFu);
            const int src = (int)((e >> 22) & 0x3Fu);
            const float QX = __shfl(qx, src);
            const float QY = __shfl(qy, src);
            const float QZ = __shfl(qz, src);

            const v4f* rp = (const v4f*)(packed + (size_t)16 * f);
            const v4f r0 = rp[0];
            const v4f r1 = rp[1];
            const v4f r2 = rp[2];
            const v4f r3 = rp[3];
            const float merged = tri_merged_pre(QX, QY, QZ,
                                                r0.x, r0.y, r0.z,
                                                r0.w, r1.x, r1.y,
                                                r1.z, r1.w, r2.x,
                                                r2.y, r2.z, r2.w,
                                                r3.x, r3.y, r3.z);
            const float am = fabsf(merged);
            const unsigned int sign = __float_as_uint(merged) >> 31;
            const unsigned long long key =
                ((unsigned long long)__float_as_uint(am) << 32)
                | ((unsigned long long)(unsigned)j << 19)
                | ((unsigned long long)sign << 18)
                | (unsigned long long)(unsigned)f;
            atomicMin(&keys[wid * 64 + src], key);
            cnt -= 64;
        }
    }

    if (cnt > 0) {
        const bool act = (unsigned)lane < cnt;
        const unsigned int e = act ? qw[lane] : 0u;
        const int f   = (int)(e & 0x3FFFFu);
        const int j   = (int)((e >> 18) & 0xFu);
        const int src = (int)((e >> 22) & 0x3Fu);
        const float QX = __shfl(qx, src);
        const float QY = __shfl(qy, src);
        const float QZ = __shfl(qz, src);

        if (act) {
            const v4f* rp = (const v4f*)(packed + (size_t)16 * f);
            const v4f r0 = rp[0];
            const v4f r1 = rp[1];
            const v4f r2 = rp[2];
            const v4f r3 = rp[3];
            const float merged = tri_merged_pre(QX, QY, QZ,
                                                r0.x, r0.y, r0.z,
                                                r0.w, r1.x, r1.y,
                                                r1.z, r1.w, r2.x,
                                                r2.y, r2.z, r2.w,
                                                r3.x, r3.y, r3.z);
            const float am = fabsf(merged);
            const unsigned int sign = __float_as_uint(merged) >> 31;
            const unsigned long long key =
                ((unsigned long long)__float_as_uint(am) << 32)
                | ((unsigned long long)(unsigned)j << 19)
                | ((unsigned long long)sign << 18)
                | (unsigned long long)(unsigned)f;
            atomicMin(&keys[wid * 64 + src], key);
        }
    }

    if (valid) {
        const unsigned long long k = keys[tid];
        const int f = (int)(k & 0x3FFFFu);
        const unsigned int sign = (unsigned int)((k >> 18) & 1u);
        const unsigned int am_bits = (unsigned int)(k >> 32);
        const float md = __uint_as_float(am_bits | (sign << 31));
        __builtin_nontemporal_store((float)f, &out_ret[qi]);
        __builtin_nontemporal_store(md,       &out_md[qi]);
    }
}

// -------- Fallback A: one-pass packed main (new record layout).
__global__ __launch_bounds__(256) void woot_main_kernel(
    const float* __restrict__ query_xyz,
    const float* __restrict__ packed,
    const int*   __restrict__ cand_ids,
    float*       __restrict__ out_ret,
    float*       __restrict__ out_md,
    int n)
{
    int i = blockIdx.x * blockDim.x + threadIdx.x;
    if (i >= n) return;

    const vf3 q = __builtin_nontemporal_load((const vf3*)(query_xyz + 3*i));
    float best_abs = 0.0f, best_md = 0.0f;
    int best_f = 0;

#pragma unroll 2
    for (int j = 0; j < C_CAND; ++j) {
        const int f = __builtin_nontemporal_load(&cand_ids[i * C_CAND + j]);
        const v4f* rp = (const v4f*)(packed + (size_t)16 * f);
        const v4f r0 = rp[0];
        const v4f r1 = rp[1];
        const v4f r2 = rp[2];
        const v4f r3 = rp[3];
        const float merged = tri_merged_pre(q.x, q.y, q.z,
                                            r0.x, r0.y, r0.z,
                                            r0.w, r1.x, r1.y,
                                            r1.z, r1.w, r2.x,
                                            r2.y, r2.z, r2.w,
                                            r3.x, r3.y, r3.z);
        const float am = fabsf(merged);
        if (j == 0 || am < best_abs) { best_abs = am; best_md = merged; best_f = f; }
    }

    __builtin_nontemporal_store((float)best_f, &out_ret[i]);
    __builtin_nontemporal_store(best_md,       &out_md[i]);
}

// -------- Fallback B: direct 3-hop kernel (no workspace needed).
__global__ __launch_bounds__(256) void woot_direct_kernel(
    const float* __restrict__ query_xyz,
    const float* __restrict__ temp_verts,
    const int*   __restrict__ faces,
    const int*   __restrict__ cand_ids,
    float*       __restrict__ out_ret,
    float*       __restrict__ out_md,
    int n)
{
    int i = blockIdx.x * blockDim.x + threadIdx.x;
    if (i >= n) return;

    const vf3 q = __builtin_nontemporal_load((const vf3*)(query_xyz + 3*i));
    float best_abs = 0.0f, best_md = 0.0f;
    int best_f = 0;

    for (int j = 0; j < C_CAND; ++j) {
        const int f = __builtin_nontemporal_load(&cand_ids[i * C_CAND + j]);
        const vi3 fi = *(const vi3*)(faces + 3*f);
        const vf3 v0 = *(const vf3*)(temp_verts + 3*fi.x);
        const vf3 v1 = *(const vf3*)(temp_verts + 3*fi.y);
        const vf3 v2 = *(const vf3*)(temp_verts + 3*fi.z);
        const float merged = tri_merged_full(q.x, q.y, q.z,
                                             v0.x, v0.y, v0.z,
                                             v1.x, v1.y, v1.z,
                                             v2.x, v2.y, v2.z);
        const float am = fabsf(merged);
        if (j == 0 || am < best_abs) { best_abs = am; best_md = merged; best_f = f; }
    }

    __builtin_nontemporal_store((float)best_f, &out_ret[i]);
    __builtin_nontemporal_store(best_md,       &out_md[i]);
}

extern "C" void kernel_launch(void* const* d_in, const int* in_sizes, int n_in,
                              void* d_out, int out_size, void* d_ws, size_t ws_size,
                              hipStream_t stream) {
    const float* query_xyz  = (const float*)d_in[0];
    const float* temp_verts = (const float*)d_in[1];
    const int*   faces      = (const int*)d_in[2];
    const int*   cand_ids   = (const int*)d_in[3];

    const int n = in_sizes[0] / 3;   // N queries
    const int F = in_sizes[2] / 3;   // number of faces

    float* out_ret = (float*)d_out;
    float* out_md  = out_ret + n;

    const int block  = 256;
    const int grid_n = (n + block - 1) / block;
    const int grid_f = (F + block - 1) / block;

    const size_t need_pack = (size_t)F * 16 * sizeof(float);  // 12.8MB

    if (ws_size >= need_pack && F <= (1 << 18)) {
        float* packed = (float*)d_ws;
        const int NS = (F + (1 << SLICE_SHIFT) - 1) >> SLICE_SHIFT;
        pack_faces_kernel<<<grid_f, block, 0, stream>>>(
            temp_verts, faces, packed, F);
        woot_sliced_kernel<<<grid_n, block, 0, stream>>>(
            query_xyz, packed, cand_ids, out_ret, out_md, n, NS);
    } else if (ws_size >= need_pack) {
        float* packed = (float*)d_ws;
        pack_faces_kernel<<<grid_f, block, 0, stream>>>(
            temp_verts, faces, packed, F);
        woot_main_kernel<<<grid_n, block, 0, stream>>>(
            query_xyz, packed, cand_ids, out_ret, out_md, n);
    } else {
        woot_direct_kernel<<<grid_n, block, 0, stream>>>(
            query_xyz, temp_verts, faces, cand_ids, out_ret, out_md, n);
    }
}